// Round 5
// baseline (283.506 us; speedup 1.0000x reference)
//
#include <hip/hip_runtime.h>
#include <math.h>

#define N_NODES 50000
#define N_EDGES 1600000
#define C 64
#define OUTC 7

#define NB 196         // coarse buckets: dst >> 8  (49999>>8 = 195)
#define BCAP 10240     // bucket capacity (mean 8192, sigma ~90)
#define CHUNK 8192     // edges per phase-1 workgroup

#define ZROW N_NODES   // zero-row index in half-tables (OOB slots sum +0.0)
#define HROW 16        // u32 per half-row (32 ch bf16 = 64 B)

typedef __attribute__((ext_vector_type(8))) short bf16x8;   // 8 bf16 = 4 VGPR
typedef __attribute__((ext_vector_type(4))) float f32x4;    // MFMA acc
typedef __attribute__((ext_vector_type(2))) float f32x2;    // packed-math pair
typedef __attribute__((ext_vector_type(4))) unsigned int u32x4;  // NT-store-able

// fp32 -> bf16 (RNE), packed pair into u32 (lo = even channel, hi = odd)
__device__ __forceinline__ unsigned int pk_bf16(float a, float b) {
    unsigned int ua = __float_as_uint(a);
    ua = (ua + 0x7FFFu + ((ua >> 16) & 1u)) >> 16;
    unsigned int ub = __float_as_uint(b);
    ub = (ub + 0x7FFFu + ((ub >> 16) & 1u)) >> 16;
    return ua | (ub << 16);
}

union U4B8 { uint4 u; bf16x8 s; };

// ---------------- prep: pack W1+W2 to bf16, zero gcursor ----------------
__global__ __launch_bounds__(256) void prep(const float* __restrict__ W1,
                                            const float* __restrict__ W2,
                                            unsigned int* __restrict__ Wb1,
                                            unsigned int* __restrict__ Wb2,
                                            int* __restrict__ gcursor) {
    const int b = blockIdx.x;
    const int tid = threadIdx.x;
    if (b < 8) {
        int idx = b * 256 + tid;
        float2 v = ((const float2*)W1)[idx];
        Wb1[idx] = pk_bf16(v.x, v.y);
    } else if (b < 16) {
        int idx = (b - 8) * 256 + tid;
        float2 v = ((const float2*)W2)[idx];
        Wb2[idx] = pk_bf16(v.x, v.y);
    } else {
        if (tid < NB) gcursor[tid] = 0;
    }
}

// ---------------- CSR build, phase 1: coarse binning ----------------
__global__ __launch_bounds__(256) void bin_kernel(const int* __restrict__ src,
                                                  const int* __restrict__ dst,
                                                  unsigned int* __restrict__ buckets,
                                                  int* __restrict__ gcursor) {
    __shared__ unsigned int staged[CHUNK];          // 32 KB
    __shared__ int hist[NB], scanb[NB], cur[NB], baseb[NB];
    const int tid = threadIdx.x;
    const int base = blockIdx.x * CHUNK;
    int n = N_EDGES - base; if (n > CHUNK) n = CHUNK;

    for (int b = tid; b < NB; b += 256) { hist[b] = 0; cur[b] = 0; }
    __syncthreads();

    const int4* src4 = (const int4*)(src + base);
    const int4* dst4 = (const int4*)(dst + base);
    unsigned int v[32];
    int nv = n >> 2;
#pragma unroll
    for (int k = 0; k < 8; ++k) {
        int i4 = k * 256 + tid;
        if (i4 < nv) {
            int4 s4 = src4[i4];
            int4 d4 = dst4[i4];
            unsigned int d0 = (unsigned int)d4.x, d1 = (unsigned int)d4.y;
            unsigned int d2 = (unsigned int)d4.z, d3 = (unsigned int)d4.w;
            v[k * 4 + 0] = (d0 << 16) | (unsigned int)s4.x;
            v[k * 4 + 1] = (d1 << 16) | (unsigned int)s4.y;
            v[k * 4 + 2] = (d2 << 16) | (unsigned int)s4.z;
            v[k * 4 + 3] = (d3 << 16) | (unsigned int)s4.w;
            atomicAdd(&hist[d0 >> 8], 1);
            atomicAdd(&hist[d1 >> 8], 1);
            atomicAdd(&hist[d2 >> 8], 1);
            atomicAdd(&hist[d3 >> 8], 1);
        }
    }
    __syncthreads();
    if (tid == 0) {
        int run = 0;
        for (int b = 0; b < NB; ++b) { scanb[b] = run; run += hist[b]; }
    }
    __syncthreads();
#pragma unroll
    for (int k = 0; k < 8; ++k) {
        int i4 = k * 256 + tid;
        if (i4 < nv) {
#pragma unroll
            for (int q = 0; q < 4; ++q) {
                unsigned int w = v[k * 4 + q];
                int b = w >> 24;
                int p = scanb[b] + atomicAdd(&cur[b], 1);
                staged[p] = w;
            }
        }
    }
    __syncthreads();
    if (tid < NB) baseb[tid] = atomicAdd(&gcursor[tid], hist[tid]);
    __syncthreads();
    for (int i = tid; i < n; i += 256) {
        unsigned int w = staged[i];
        int b = w >> 24;
        buckets[(size_t)b * BCAP + baseb[b] + (i - scanb[b])] = w;
    }
}

// ---------------- CSR build, phase 2: per-bucket local CSR ----------------
__global__ __launch_bounds__(256) void build_csr(const unsigned int* __restrict__ buckets,
                                                 const int* __restrict__ gcursor,
                                                 unsigned int* __restrict__ csr,
                                                 int* __restrict__ off) {
    __shared__ int hist[256], part[256], offx[256], cur[256];
    __shared__ int gl[NB];
    __shared__ int s_cnt, s_base;
    const int tid = threadIdx.x;
    const int b = blockIdx.x;

    hist[tid] = 0;
    cur[tid] = 0;
    if (tid < NB) gl[tid] = gcursor[tid];
    __syncthreads();
    if (tid == 0) {
        int bs = 0;
        for (int i = 0; i < b; ++i) bs += gl[i];
        s_base = bs;
        s_cnt = gl[b];
    }
    __syncthreads();
    const int cnt = s_cnt;
    const int gbase = s_base;
    const unsigned int* bk = buckets + (size_t)b * BCAP;

    for (int i = tid; i < cnt; i += 256) {
        atomicAdd(&hist[(bk[i] >> 16) & 255], 1);
    }
    __syncthreads();
    part[tid] = hist[tid];
    __syncthreads();
    for (int d = 1; d < 256; d <<= 1) {
        int t = (tid >= d) ? part[tid - d] : 0;
        __syncthreads();
        part[tid] += t;
        __syncthreads();
    }
    offx[tid] = (tid == 0) ? 0 : part[tid - 1];
    __syncthreads();
    int node = b * 256 + tid;
    if (node < N_NODES) off[node] = gbase + offx[tid];
    if (b == NB - 1 && tid == 0) off[N_NODES] = gbase + cnt;
    for (int i = tid; i < cnt; i += 256) {
        unsigned int w = bk[i];
        int dl = (w >> 16) & 255;
        int p = offx[dl] + atomicAdd(&cur[dl], 1);
        csr[gbase + p] = w & 0xFFFFu;
    }
}

// ---------------- MFMA linears (split half-table outputs) ----------------
// One wave = 16 rows x 64 cols via 8x mfma_f32_16x16x32_bf16.
// Layout rule (verified r0-r3): u32 index g in a row <-> channels (2g, 2g+1).
// Split: g<16 -> half A, g>=16 -> half B (each half-row = 16 u32 = 64 B).
// Block 0 zeroes ZROW half-rows (the gather zero-row).

// Layer 1: fp32 x in (A-frag packed in-register), split bf16 t out.
__global__ __launch_bounds__(256) void linear64_mfma_x(const float* __restrict__ x,
                                                       const unsigned int* __restrict__ Wb,
                                                       unsigned int* __restrict__ outA,
                                                       unsigned int* __restrict__ outB) {
    if (blockIdx.x == 0 && threadIdx.x < 16) {
        outA[(size_t)ZROW * HROW + threadIdx.x] = 0u;
        outB[(size_t)ZROW * HROW + threadIdx.x] = 0u;
    }
    const int wave = threadIdx.x >> 6;
    const int lane = threadIdx.x & 63;
    const int quad = lane >> 4;
    const int l16  = lane & 15;
    const int rbase = blockIdx.x * 64 + wave * 16;
    if (rbase >= N_NODES) return;

    U4B8 bfrag[4][2];
#pragma unroll
    for (int ct = 0; ct < 4; ++ct)
#pragma unroll
        for (int kt = 0; kt < 2; ++kt)
            bfrag[ct][kt].u = *(const uint4*)(Wb + (ct * 16 + l16) * 32 + kt * 16 + quad * 4);

    U4B8 afrag[2];
#pragma unroll
    for (int kt = 0; kt < 2; ++kt) {
        const float4* xp = (const float4*)(x + (size_t)(rbase + l16) * 64 + kt * 32 + quad * 8);
        float4 f0 = xp[0];
        float4 f1 = xp[1];
        afrag[kt].u.x = pk_bf16(f0.x, f0.y);
        afrag[kt].u.y = pk_bf16(f0.z, f0.w);
        afrag[kt].u.z = pk_bf16(f1.x, f1.y);
        afrag[kt].u.w = pk_bf16(f1.z, f1.w);
    }

    f32x4 acc[4];
#pragma unroll
    for (int ct = 0; ct < 4; ++ct) {
        f32x4 z = {0.f, 0.f, 0.f, 0.f};
        z = __builtin_amdgcn_mfma_f32_16x16x32_bf16(afrag[0].s, bfrag[ct][0].s, z, 0, 0, 0);
        z = __builtin_amdgcn_mfma_f32_16x16x32_bf16(afrag[1].s, bfrag[ct][1].s, z, 0, 0, 0);
        acc[ct] = z;
    }

    const int colp = l16 >> 1;
    const bool even = (l16 & 1) == 0;
#pragma unroll
    for (int ct = 0; ct < 4; ++ct) {
        unsigned int* outh = (ct < 2) ? outA : outB;
        const int cg = (ct & 1) * 8 + colp;
#pragma unroll
        for (int i = 0; i < 4; ++i) {
            float v = acc[ct][i];
            float p = __shfl_xor(v, 1, 64);
            if (even) {
                int row = rbase + quad * 4 + i;
                outh[(size_t)row * HROW + cg] = pk_bf16(v, p);
            }
        }
    }
}

// Layer 2: split bf16 h in, split bf16 t out.
__global__ __launch_bounds__(256) void linear64_mfma(const unsigned int* __restrict__ inA,
                                                     const unsigned int* __restrict__ inB,
                                                     const unsigned int* __restrict__ Wb,
                                                     unsigned int* __restrict__ outA,
                                                     unsigned int* __restrict__ outB) {
    if (blockIdx.x == 0 && threadIdx.x < 16) {
        outA[(size_t)ZROW * HROW + threadIdx.x] = 0u;
        outB[(size_t)ZROW * HROW + threadIdx.x] = 0u;
    }
    const int wave = threadIdx.x >> 6;
    const int lane = threadIdx.x & 63;
    const int quad = lane >> 4;
    const int l16  = lane & 15;
    const int rbase = blockIdx.x * 64 + wave * 16;
    if (rbase >= N_NODES) return;

    U4B8 bfrag[4][2];
#pragma unroll
    for (int ct = 0; ct < 4; ++ct)
#pragma unroll
        for (int kt = 0; kt < 2; ++kt)
            bfrag[ct][kt].u = *(const uint4*)(Wb + (ct * 16 + l16) * 32 + kt * 16 + quad * 4);

    U4B8 afrag[2];
    afrag[0].u = *(const uint4*)(inA + (size_t)(rbase + l16) * HROW + quad * 4);
    afrag[1].u = *(const uint4*)(inB + (size_t)(rbase + l16) * HROW + quad * 4);

    f32x4 acc[4];
#pragma unroll
    for (int ct = 0; ct < 4; ++ct) {
        f32x4 z = {0.f, 0.f, 0.f, 0.f};
        z = __builtin_amdgcn_mfma_f32_16x16x32_bf16(afrag[0].s, bfrag[ct][0].s, z, 0, 0, 0);
        z = __builtin_amdgcn_mfma_f32_16x16x32_bf16(afrag[1].s, bfrag[ct][1].s, z, 0, 0, 0);
        acc[ct] = z;
    }

    const int colp = l16 >> 1;
    const bool even = (l16 & 1) == 0;
#pragma unroll
    for (int ct = 0; ct < 4; ++ct) {
        unsigned int* outh = (ct < 2) ? outA : outB;
        const int cg = (ct & 1) * 8 + colp;
#pragma unroll
        for (int i = 0; i < 4; ++i) {
            float v = acc[ct][i];
            float p = __shfl_xor(v, 1, 64);
            if (even) {
                int row = rbase + quad * 4 + i;
                outh[(size_t)row * HROW + cg] = pk_bf16(v, p);
            }
        }
    }
}

// ---------------- half-table gathers (L2-resident 3.2 MB working set) -------
// 16 slots x 4 ch-lanes x uint4; 2 edges in flight/lane -> one-shot 32 edges.
// OOB slots redirect to the zeroed ZROW row (csr over-read <=31 lands in off).
#define ACCQ(v)                                                              \
    do {                                                                     \
        q0 += (f32x2){__uint_as_float((v).x << 16),                          \
                      __uint_as_float((v).x & 0xFFFF0000u)};                 \
        q1 += (f32x2){__uint_as_float((v).y << 16),                          \
                      __uint_as_float((v).y & 0xFFFF0000u)};                 \
        q2 += (f32x2){__uint_as_float((v).z << 16),                          \
                      __uint_as_float((v).z & 0xFFFF0000u)};                 \
        q3 += (f32x2){__uint_as_float((v).w << 16),                          \
                      __uint_as_float((v).w & 0xFFFF0000u)};                 \
    } while (0)

#define QREDUCE()                                                            \
    do {                                                                     \
        _Pragma("unroll")                                                    \
        for (int d = 4; d <= 32; d <<= 1) {                                  \
            q0.x += __shfl_xor(q0.x, d, 64); q0.y += __shfl_xor(q0.y, d, 64);\
            q1.x += __shfl_xor(q1.x, d, 64); q1.y += __shfl_xor(q1.y, d, 64);\
            q2.x += __shfl_xor(q2.x, d, 64); q2.y += __shfl_xor(q2.y, d, 64);\
            q3.x += __shfl_xor(q3.x, d, 64); q3.y += __shfl_xor(q3.y, d, 64);\
        }                                                                    \
    } while (0)

// layer-1/2 aggregation over one channel half: t-half -> h-half (bias+relu).
// h stores are non-temporal so the resident t-half isn't evicted.
__global__ __launch_bounds__(256) void gather_h_half(const int* __restrict__ off,
                                                     const unsigned int* __restrict__ csr_src,
                                                     const unsigned int* __restrict__ th,
                                                     const float* __restrict__ b,
                                                     unsigned int* __restrict__ hh,
                                                     int half) {
    int node = blockIdx.x * 4 + (threadIdx.x >> 6);
    if (node >= N_NODES) return;
    const int lane = threadIdx.x & 63;
    const int slot = lane >> 2;        // 16 slots
    const int ln   = lane & 3;         // 4 ch-lanes (8 ch each)
    int e0 = off[node], e1 = off[node + 1];
    const uint4* t4 = (const uint4*)th;   // half-row = 4 uint4
    f32x2 q0 = {0.f, 0.f}, q1 = {0.f, 0.f}, q2 = {0.f, 0.f}, q3 = {0.f, 0.f};
    for (int e = e0; e < e1; e += 32) {
        int i0 = e + slot, i1 = i0 + 16;
        unsigned int a0 = csr_src[i0];
        unsigned int a1 = csr_src[i1];
        a0 = (i0 < e1) ? a0 : ZROW;
        a1 = (i1 < e1) ? a1 : ZROW;
        uint4 v0 = t4[(size_t)a0 * 4 + ln];
        uint4 v1 = t4[(size_t)a1 * 4 + ln];
        ACCQ(v0);
        ACCQ(v1);
    }
    QREDUCE();
    if (lane < 4) {
        const int cb = half * 32 + ln * 8;
        float r0 = fmaxf(q0.x + b[cb + 0], 0.f);
        float r1 = fmaxf(q0.y + b[cb + 1], 0.f);
        float r2 = fmaxf(q1.x + b[cb + 2], 0.f);
        float r3 = fmaxf(q1.y + b[cb + 3], 0.f);
        float r4 = fmaxf(q2.x + b[cb + 4], 0.f);
        float r5 = fmaxf(q2.y + b[cb + 5], 0.f);
        float r6 = fmaxf(q3.x + b[cb + 6], 0.f);
        float r7 = fmaxf(q3.y + b[cb + 7], 0.f);
        u32x4 w;
        w.x = pk_bf16(r0, r1);
        w.y = pk_bf16(r2, r3);
        w.z = pk_bf16(r4, r5);
        w.w = pk_bf16(r6, r7);
        __builtin_nontemporal_store(w, (u32x4*)(hh + (size_t)node * HROW) + ln);
    }
}

// layer-2 aggregation half + bias + relu + partial W3 projection -> f32 t3
// via atomicAdd (2 adds per cell total; t3f pre-zeroed by memset).
__global__ __launch_bounds__(256) void gather_w3_half(const int* __restrict__ off,
                                                      const unsigned int* __restrict__ csr_src,
                                                      const unsigned int* __restrict__ th,
                                                      const float* __restrict__ b,
                                                      const float* __restrict__ W3,
                                                      float* __restrict__ t3f,
                                                      int half) {
    int node = blockIdx.x * 4 + (threadIdx.x >> 6);
    if (node >= N_NODES) return;
    const int lane = threadIdx.x & 63;
    const int slot = lane >> 2;
    const int ln   = lane & 3;
    int e0 = off[node], e1 = off[node + 1];
    const uint4* t4 = (const uint4*)th;
    f32x2 q0 = {0.f, 0.f}, q1 = {0.f, 0.f}, q2 = {0.f, 0.f}, q3 = {0.f, 0.f};
    for (int e = e0; e < e1; e += 32) {
        int i0 = e + slot, i1 = i0 + 16;
        unsigned int a0 = csr_src[i0];
        unsigned int a1 = csr_src[i1];
        a0 = (i0 < e1) ? a0 : ZROW;
        a1 = (i1 < e1) ? a1 : ZROW;
        uint4 v0 = t4[(size_t)a0 * 4 + ln];
        uint4 v1 = t4[(size_t)a1 * 4 + ln];
        ACCQ(v0);
        ACCQ(v1);
    }
    QREDUCE();
    const int cb = half * 32 + ln * 8;
    float r0 = fmaxf(q0.x + b[cb + 0], 0.f);
    float r1 = fmaxf(q0.y + b[cb + 1], 0.f);
    float r2 = fmaxf(q1.x + b[cb + 2], 0.f);
    float r3 = fmaxf(q1.y + b[cb + 3], 0.f);
    float r4 = fmaxf(q2.x + b[cb + 4], 0.f);
    float r5 = fmaxf(q2.y + b[cb + 5], 0.f);
    float r6 = fmaxf(q3.x + b[cb + 6], 0.f);
    float r7 = fmaxf(q3.y + b[cb + 7], 0.f);
#pragma unroll
    for (int j = 0; j < 7; ++j) {
        const float4 wa = *(const float4*)(W3 + j * 64 + cb);
        const float4 wb = *(const float4*)(W3 + j * 64 + cb + 4);
        float t = r0 * wa.x + r1 * wa.y + r2 * wa.z + r3 * wa.w
                + r4 * wb.x + r5 * wb.y + r6 * wb.z + r7 * wb.w;
        t += __shfl_xor(t, 1, 64);    // sum the 4 ch-lane classes
        t += __shfl_xor(t, 2, 64);
        if (lane == 0) atomicAdd(t3f + (size_t)node * 8 + j, t);
    }
}

// 7-ch gather + bias + log_softmax (f32 t3, 32 B rows, 1.6 MB L2-resident).
__global__ __launch_bounds__(256) void gather7_lsm(const int* __restrict__ off,
                                                   const unsigned int* __restrict__ csr_src,
                                                   const float* __restrict__ t3f,
                                                   const float* __restrict__ b,
                                                   float* __restrict__ out) {
    int node = blockIdx.x * 4 + (threadIdx.x >> 6);
    if (node >= N_NODES) return;
    const int lane = threadIdx.x & 63;
    const int slot = lane >> 1;
    const int h    = lane & 1;
    int e0 = off[node], e1 = off[node + 1];
    const float4* t4 = (const float4*)t3f;
    float sx = 0.f, sy = 0.f, sz = 0.f, sw = 0.f;
    for (int e = e0 + slot; e < e1; e += 32) {
        unsigned int a = csr_src[e];
        float4 v = t4[(size_t)a * 2 + h];
        sx += v.x; sy += v.y; sz += v.z; sw += v.w;
    }
#pragma unroll
    for (int d = 2; d <= 32; d <<= 1) {
        sx += __shfl_xor(sx, d, 64); sy += __shfl_xor(sy, d, 64);
        sz += __shfl_xor(sz, d, 64); sw += __shfl_xor(sw, d, 64);
    }
    float z0 = sx + b[h * 4 + 0];
    float z1 = sy + b[h * 4 + 1];
    float z2 = sz + b[h * 4 + 2];
    float z3 = (h == 0) ? (sw + b[3]) : -1e30f;
    float m = fmaxf(fmaxf(z0, z1), fmaxf(z2, z3));
    m = fmaxf(m, __shfl_xor(m, 1, 64));
    float ex = __expf(z0 - m) + __expf(z1 - m) + __expf(z2 - m) + __expf(z3 - m);
    ex += __shfl_xor(ex, 1, 64);
    float l = m + __logf(ex);
    if (lane < 2) {
        float* o = out + (size_t)node * 7 + h * 4;
        o[0] = z0 - l; o[1] = z1 - l; o[2] = z2 - l;
        if (h == 0) o[3] = z3 - l;
    }
}

extern "C" void kernel_launch(void* const* d_in, const int* in_sizes, int n_in,
                              void* d_out, int out_size, void* d_ws, size_t ws_size,
                              hipStream_t stream) {
    const float* x  = (const float*)d_in[0];
    const int*   ei = (const int*)d_in[1];
    const float* W1 = (const float*)d_in[2];
    const float* b1 = (const float*)d_in[3];
    const float* W2 = (const float*)d_in[4];
    const float* b2 = (const float*)d_in[5];
    const float* W3 = (const float*)d_in[6];
    const float* b3 = (const float*)d_in[7];
    float* out = (float*)d_out;

    const int* src = ei;
    const int* dst = ei + N_EDGES;

    // workspace (u32 units):
    //   tA,tB: 3.2 MB half t-tables (+ ZROW row)   [buckets 8 MB aliases tA..hA]
    //   hA,hB: 3.2 MB half h-tables
    //   t3f:   1.6 MB f32 W3-partials (memset 0)
    //   csr:   6.4 MB (over-read <=31 u32 lands in off), off, gcursor, Wb1/Wb2
    const size_t HT = (size_t)(N_NODES + 1) * HROW;   // 800016 u32
    unsigned int* tA = (unsigned int*)d_ws;
    unsigned int* tB = tA + HT;
    unsigned int* hA = tB + HT;
    unsigned int* hB = hA + HT;
    float* t3f = (float*)(hB + HT);                    // (N_NODES+1)*8 f32
    unsigned int* csr = (unsigned int*)(t3f + (size_t)(N_NODES + 1) * 8);
    int* off     = (int*)(csr + N_EDGES);              // 50001
    int* gcursor = off + N_NODES + 8;                  // 196
    unsigned int* Wb1 = (unsigned int*)(gcursor + 256);
    unsigned int* Wb2 = Wb1 + 2048;
    unsigned int* buckets = tA;                        // 8 MB alias, dead after build

    const int mfmagrid = (N_NODES + 63) / 64;          // 782 blocks x 4 waves
    const int ngrid    = (N_NODES + 3) / 4;            // 12500

    // ---- t3 accumulator zero + prep
    (void)hipMemsetAsync(t3f, 0, (size_t)(N_NODES + 1) * 8 * sizeof(float), stream);
    prep<<<17, 256, 0, stream>>>(W1, W2, Wb1, Wb2, gcursor);

    // ---- CSR build
    bin_kernel<<<(N_EDGES + CHUNK - 1) / CHUNK, 256, 0, stream>>>(src, dst, buckets, gcursor);
    build_csr<<<NB, 256, 0, stream>>>(buckets, gcursor, csr, off);

    // ---- layer 1 (tA/tB overwrite buckets: must follow build_csr)
    linear64_mfma_x<<<mfmagrid, 256, 0, stream>>>(x, Wb1, tA, tB);
    gather_h_half<<<ngrid, 256, 0, stream>>>(off, csr, tA, b1, hA, 0);
    gather_h_half<<<ngrid, 256, 0, stream>>>(off, csr, tB, b1, hB, 1);

    // ---- layer 2 linear
    linear64_mfma<<<mfmagrid, 256, 0, stream>>>(hA, hB, Wb2, tA, tB);

    // ---- layer 2 gather + fused partial W3 (h2 never hits memory)
    gather_w3_half<<<ngrid, 256, 0, stream>>>(off, csr, tA, b2, W3, t3f, 0);
    gather_w3_half<<<ngrid, 256, 0, stream>>>(off, csr, tB, b2, W3, t3f, 1);

    // ---- layer 3 aggregation + log_softmax
    gather7_lsm<<<ngrid, 256, 0, stream>>>(off, csr, t3f, b3, out);
}

// Round 6
// 229.457 us; speedup vs baseline: 1.2356x; 1.2356x over previous
//
#include <hip/hip_runtime.h>
#include <math.h>

#define N_NODES 50000
#define N_EDGES 1600000
#define C 64
#define OUTC 7

#define NB 196         // coarse buckets: dst >> 8  (49999>>8 = 195)
#define BCAP 10240     // bucket capacity (mean 8192, sigma ~90)
#define CHUNK 8192     // edges per phase-1 workgroup

#define ZROW N_NODES   // zero-row index in the t-table (OOB slots sum +0.0)

typedef __attribute__((ext_vector_type(8))) short bf16x8;   // 8 bf16 = 4 VGPR
typedef __attribute__((ext_vector_type(4))) float f32x4;    // MFMA acc
typedef __attribute__((ext_vector_type(2))) float f32x2;    // packed-math pair

// fp32 -> bf16 (RNE), packed pair into u32 (lo = even channel, hi = odd)
__device__ __forceinline__ unsigned int pk_bf16(float a, float b) {
    unsigned int ua = __float_as_uint(a);
    ua = (ua + 0x7FFFu + ((ua >> 16) & 1u)) >> 16;
    unsigned int ub = __float_as_uint(b);
    ub = (ub + 0x7FFFu + ((ub >> 16) & 1u)) >> 16;
    return ua | (ub << 16);
}

union U4B8 { uint4 u; bf16x8 s; };

// ---------------- prep: pack W1+W2 to bf16, zero gcursor ----------------
__global__ __launch_bounds__(256) void prep(const float* __restrict__ W1,
                                            const float* __restrict__ W2,
                                            unsigned int* __restrict__ Wb1,
                                            unsigned int* __restrict__ Wb2,
                                            int* __restrict__ gcursor) {
    const int b = blockIdx.x;
    const int tid = threadIdx.x;
    if (b < 8) {
        int idx = b * 256 + tid;
        float2 v = ((const float2*)W1)[idx];
        Wb1[idx] = pk_bf16(v.x, v.y);
    } else if (b < 16) {
        int idx = (b - 8) * 256 + tid;
        float2 v = ((const float2*)W2)[idx];
        Wb2[idx] = pk_bf16(v.x, v.y);
    } else {
        if (tid < NB) gcursor[tid] = 0;
    }
}

// ---------------- CSR build, phase 1: coarse binning ----------------
__global__ __launch_bounds__(256) void bin_kernel(const int* __restrict__ src,
                                                  const int* __restrict__ dst,
                                                  unsigned int* __restrict__ buckets,
                                                  int* __restrict__ gcursor) {
    __shared__ unsigned int staged[CHUNK];          // 32 KB
    __shared__ int hist[NB], scanb[NB], cur[NB], baseb[NB];
    const int tid = threadIdx.x;
    const int base = blockIdx.x * CHUNK;
    int n = N_EDGES - base; if (n > CHUNK) n = CHUNK;

    for (int b = tid; b < NB; b += 256) { hist[b] = 0; cur[b] = 0; }
    __syncthreads();

    const int4* src4 = (const int4*)(src + base);
    const int4* dst4 = (const int4*)(dst + base);
    unsigned int v[32];
    int nv = n >> 2;
#pragma unroll
    for (int k = 0; k < 8; ++k) {
        int i4 = k * 256 + tid;
        if (i4 < nv) {
            int4 s4 = src4[i4];
            int4 d4 = dst4[i4];
            unsigned int d0 = (unsigned int)d4.x, d1 = (unsigned int)d4.y;
            unsigned int d2 = (unsigned int)d4.z, d3 = (unsigned int)d4.w;
            v[k * 4 + 0] = (d0 << 16) | (unsigned int)s4.x;
            v[k * 4 + 1] = (d1 << 16) | (unsigned int)s4.y;
            v[k * 4 + 2] = (d2 << 16) | (unsigned int)s4.z;
            v[k * 4 + 3] = (d3 << 16) | (unsigned int)s4.w;
            atomicAdd(&hist[d0 >> 8], 1);
            atomicAdd(&hist[d1 >> 8], 1);
            atomicAdd(&hist[d2 >> 8], 1);
            atomicAdd(&hist[d3 >> 8], 1);
        }
    }
    __syncthreads();
    if (tid == 0) {
        int run = 0;
        for (int b = 0; b < NB; ++b) { scanb[b] = run; run += hist[b]; }
    }
    __syncthreads();
#pragma unroll
    for (int k = 0; k < 8; ++k) {
        int i4 = k * 256 + tid;
        if (i4 < nv) {
#pragma unroll
            for (int q = 0; q < 4; ++q) {
                unsigned int w = v[k * 4 + q];
                int b = w >> 24;
                int p = scanb[b] + atomicAdd(&cur[b], 1);
                staged[p] = w;
            }
        }
    }
    __syncthreads();
    if (tid < NB) baseb[tid] = atomicAdd(&gcursor[tid], hist[tid]);
    __syncthreads();
    for (int i = tid; i < n; i += 256) {
        unsigned int w = staged[i];
        int b = w >> 24;
        buckets[(size_t)b * BCAP + baseb[b] + (i - scanb[b])] = w;
    }
}

// ---------------- CSR build, phase 2: per-bucket local CSR ----------------
__global__ __launch_bounds__(256) void build_csr(const unsigned int* __restrict__ buckets,
                                                 const int* __restrict__ gcursor,
                                                 unsigned int* __restrict__ csr,
                                                 int* __restrict__ off) {
    __shared__ int hist[256], part[256], offx[256], cur[256];
    __shared__ int gl[NB];
    __shared__ int s_cnt, s_base;
    const int tid = threadIdx.x;
    const int b = blockIdx.x;

    hist[tid] = 0;
    cur[tid] = 0;
    if (tid < NB) gl[tid] = gcursor[tid];
    __syncthreads();
    if (tid == 0) {
        int bs = 0;
        for (int i = 0; i < b; ++i) bs += gl[i];
        s_base = bs;
        s_cnt = gl[b];
    }
    __syncthreads();
    const int cnt = s_cnt;
    const int gbase = s_base;
    const unsigned int* bk = buckets + (size_t)b * BCAP;

    for (int i = tid; i < cnt; i += 256) {
        atomicAdd(&hist[(bk[i] >> 16) & 255], 1);
    }
    __syncthreads();
    part[tid] = hist[tid];
    __syncthreads();
    for (int d = 1; d < 256; d <<= 1) {
        int t = (tid >= d) ? part[tid - d] : 0;
        __syncthreads();
        part[tid] += t;
        __syncthreads();
    }
    offx[tid] = (tid == 0) ? 0 : part[tid - 1];
    __syncthreads();
    int node = b * 256 + tid;
    if (node < N_NODES) off[node] = gbase + offx[tid];
    if (b == NB - 1 && tid == 0) off[N_NODES] = gbase + cnt;
    for (int i = tid; i < cnt; i += 256) {
        unsigned int w = bk[i];
        int dl = (w >> 16) & 255;
        int p = offx[dl] + atomicAdd(&cur[dl], 1);
        csr[gbase + p] = w & 0xFFFFu;
    }
}

// ---------------- MFMA linears ----------------
// One wave = 16 rows x 64 cols via 8x mfma_f32_16x16x32_bf16.
// A frag: m=lane&15, k=quad*8+j. W stored [n][k] == B^T -> same pattern.
// D: col=lane&15, row=quad*4+reg. Block 0 zeroes t-table row ZROW.

// Layer 1: fp32 x in (A-frag packed in-register), bf16 t out.
__global__ __launch_bounds__(256) void linear64_mfma_x(const float* __restrict__ x,
                                                       const unsigned int* __restrict__ Wb,
                                                       unsigned int* __restrict__ out) {
    if (blockIdx.x == 0 && threadIdx.x < 32)
        out[(size_t)ZROW * 32 + threadIdx.x] = 0u;
    const int wave = threadIdx.x >> 6;
    const int lane = threadIdx.x & 63;
    const int quad = lane >> 4;
    const int l16  = lane & 15;
    const int rbase = blockIdx.x * 64 + wave * 16;
    if (rbase >= N_NODES) return;

    U4B8 bfrag[4][2];
#pragma unroll
    for (int ct = 0; ct < 4; ++ct)
#pragma unroll
        for (int kt = 0; kt < 2; ++kt)
            bfrag[ct][kt].u = *(const uint4*)(Wb + (ct * 16 + l16) * 32 + kt * 16 + quad * 4);

    U4B8 afrag[2];
#pragma unroll
    for (int kt = 0; kt < 2; ++kt) {
        const float4* xp = (const float4*)(x + (size_t)(rbase + l16) * 64 + kt * 32 + quad * 8);
        float4 f0 = xp[0];
        float4 f1 = xp[1];
        afrag[kt].u.x = pk_bf16(f0.x, f0.y);
        afrag[kt].u.y = pk_bf16(f0.z, f0.w);
        afrag[kt].u.z = pk_bf16(f1.x, f1.y);
        afrag[kt].u.w = pk_bf16(f1.z, f1.w);
    }

    f32x4 acc[4];
#pragma unroll
    for (int ct = 0; ct < 4; ++ct) {
        f32x4 z = {0.f, 0.f, 0.f, 0.f};
        z = __builtin_amdgcn_mfma_f32_16x16x32_bf16(afrag[0].s, bfrag[ct][0].s, z, 0, 0, 0);
        z = __builtin_amdgcn_mfma_f32_16x16x32_bf16(afrag[1].s, bfrag[ct][1].s, z, 0, 0, 0);
        acc[ct] = z;
    }

    const int colp = l16 >> 1;
    const bool even = (l16 & 1) == 0;
#pragma unroll
    for (int ct = 0; ct < 4; ++ct) {
#pragma unroll
        for (int i = 0; i < 4; ++i) {
            float v = acc[ct][i];
            float p = __shfl_xor(v, 1, 64);
            if (even) {
                int row = rbase + quad * 4 + i;
                out[(size_t)row * 32 + ct * 8 + colp] = pk_bf16(v, p);
            }
        }
    }
}

// Layer 2: bf16 table in, bf16 t out.
__global__ __launch_bounds__(256) void linear64_mfma(const unsigned int* __restrict__ in,
                                                     const unsigned int* __restrict__ Wb,
                                                     unsigned int* __restrict__ out) {
    if (blockIdx.x == 0 && threadIdx.x < 32)
        out[(size_t)ZROW * 32 + threadIdx.x] = 0u;
    const int wave = threadIdx.x >> 6;
    const int lane = threadIdx.x & 63;
    const int quad = lane >> 4;
    const int l16  = lane & 15;
    const int rbase = blockIdx.x * 64 + wave * 16;
    if (rbase >= N_NODES) return;

    U4B8 bfrag[4][2];
#pragma unroll
    for (int ct = 0; ct < 4; ++ct)
#pragma unroll
        for (int kt = 0; kt < 2; ++kt)
            bfrag[ct][kt].u = *(const uint4*)(Wb + (ct * 16 + l16) * 32 + kt * 16 + quad * 4);

    U4B8 afrag[2];
#pragma unroll
    for (int kt = 0; kt < 2; ++kt)
        afrag[kt].u = *(const uint4*)(in + (size_t)(rbase + l16) * 32 + kt * 16 + quad * 4);

    f32x4 acc[4];
#pragma unroll
    for (int ct = 0; ct < 4; ++ct) {
        f32x4 z = {0.f, 0.f, 0.f, 0.f};
        z = __builtin_amdgcn_mfma_f32_16x16x32_bf16(afrag[0].s, bfrag[ct][0].s, z, 0, 0, 0);
        z = __builtin_amdgcn_mfma_f32_16x16x32_bf16(afrag[1].s, bfrag[ct][1].s, z, 0, 0, 0);
        acc[ct] = z;
    }

    const int colp = l16 >> 1;
    const bool even = (l16 & 1) == 0;
#pragma unroll
    for (int ct = 0; ct < 4; ++ct) {
#pragma unroll
        for (int i = 0; i < 4; ++i) {
            float v = acc[ct][i];
            float p = __shfl_xor(v, 1, 64);
            if (even) {
                int row = rbase + quad * 4 + i;
                out[(size_t)row * 32 + ct * 8 + colp] = pk_bf16(v, p);
            }
        }
    }
}

// ---------------- gather aggregation: K=4 nodes per wave ----------------
// Each wave owns 4 consecutive nodes. Issue ALL csr loads (16), then ALL
// t-row loads (16, 4 independent chains overlapped), then accumulate/reduce/
// store per node. OOB slots -> zeroed ZROW row, unconditional accumulate.
// deg>32 tail handled by a per-node loop (rare: ~50% of nodes, 1 extra trip).
// csr over-read (<=31 u32) lands in the adjacent 'off' array (readable).
#define ACC8(v)                                                              \
    do {                                                                     \
        s01 += (f32x2){__uint_as_float((v).x << 16),                         \
                       __uint_as_float((v).x & 0xFFFF0000u)};                \
        s23 += (f32x2){__uint_as_float((v).y << 16),                         \
                       __uint_as_float((v).y & 0xFFFF0000u)};                \
        s45 += (f32x2){__uint_as_float((v).z << 16),                         \
                       __uint_as_float((v).z & 0xFFFF0000u)};                \
        s67 += (f32x2){__uint_as_float((v).w << 16),                         \
                       __uint_as_float((v).w & 0xFFFF0000u)};                \
    } while (0)

__global__ __launch_bounds__(256) void gather64b(const int* __restrict__ off,
                                                 const unsigned int* __restrict__ csr_src,
                                                 const unsigned int* __restrict__ tb,
                                                 const float* __restrict__ b,
                                                 unsigned int* __restrict__ hb) {
    const int wave = threadIdx.x >> 6;
    const int lane = threadIdx.x & 63;
    const int slot = lane >> 3;
    const int ch8  = lane & 7;
    const int n0 = (blockIdx.x * 4 + wave) * 4;
    if (n0 >= N_NODES) return;
    const uint4* t4 = (const uint4*)tb;

    int eb[5];
#pragma unroll
    for (int k = 0; k < 5; ++k) eb[k] = off[n0 + k];

    unsigned int idx[4][4];
#pragma unroll
    for (int k = 0; k < 4; ++k) {
        int e0 = eb[k], e1 = eb[k + 1];
#pragma unroll
        for (int j = 0; j < 4; ++j) {
            int i = e0 + slot + j * 8;
            unsigned int av = csr_src[i];
            idx[k][j] = (i < e1) ? av : ZROW;
        }
    }
    uint4 tv[4][4];
#pragma unroll
    for (int k = 0; k < 4; ++k)
#pragma unroll
        for (int j = 0; j < 4; ++j)
            tv[k][j] = t4[(size_t)idx[k][j] * 8 + ch8];

#pragma unroll
    for (int k = 0; k < 4; ++k) {
        f32x2 s01 = {0.f, 0.f}, s23 = {0.f, 0.f}, s45 = {0.f, 0.f}, s67 = {0.f, 0.f};
        ACC8(tv[k][0]);
        ACC8(tv[k][1]);
        ACC8(tv[k][2]);
        ACC8(tv[k][3]);
        const int e1 = eb[k + 1];
        for (int e = eb[k] + 32; e < e1; e += 32) {   // rare tail
#pragma unroll
            for (int j = 0; j < 4; ++j) {
                int i = e + slot + j * 8;
                unsigned int av = csr_src[i];
                av = (i < e1) ? av : ZROW;
                uint4 v = t4[(size_t)av * 8 + ch8];
                ACC8(v);
            }
        }
        float s[8] = {s01.x, s01.y, s23.x, s23.y, s45.x, s45.y, s67.x, s67.y};
#pragma unroll
        for (int d = 8; d <= 32; d <<= 1) {
#pragma unroll
            for (int j = 0; j < 8; ++j) s[j] += __shfl_xor(s[j], d, 64);
        }
        if (lane < 8) {
            const float4 b0 = ((const float4*)b)[ch8 * 2];
            const float4 b1 = ((const float4*)b)[ch8 * 2 + 1];
            float r0 = fmaxf(s[0] + b0.x, 0.f);
            float r1 = fmaxf(s[1] + b0.y, 0.f);
            float r2 = fmaxf(s[2] + b0.z, 0.f);
            float r3 = fmaxf(s[3] + b0.w, 0.f);
            float r4 = fmaxf(s[4] + b1.x, 0.f);
            float r5 = fmaxf(s[5] + b1.y, 0.f);
            float r6 = fmaxf(s[6] + b1.z, 0.f);
            float r7 = fmaxf(s[7] + b1.w, 0.f);
            uint4 w;
            w.x = pk_bf16(r0, r1);
            w.y = pk_bf16(r2, r3);
            w.z = pk_bf16(r4, r5);
            w.w = pk_bf16(r6, r7);
            ((uint4*)(hb + (size_t)(n0 + k) * 32))[ch8] = w;
        }
    }
}

// Layer-2 gather (K=4) + bias + relu + FUSED W3 projection -> t3 (16 B rows).
// Block 0 zeroes t3 row ZROW for gather7_lsm's ZROW redirect.
__global__ __launch_bounds__(256) void gather64b_w3(const int* __restrict__ off,
                                                    const unsigned int* __restrict__ csr_src,
                                                    const unsigned int* __restrict__ tb,
                                                    const float* __restrict__ b,
                                                    const float* __restrict__ W3,
                                                    unsigned int* __restrict__ t3) {
    if (blockIdx.x == 0 && threadIdx.x < 4)
        t3[(size_t)ZROW * 4 + threadIdx.x] = 0u;
    const int wave = threadIdx.x >> 6;
    const int lane = threadIdx.x & 63;
    const int slot = lane >> 3;
    const int ch8  = lane & 7;
    const int n0 = (blockIdx.x * 4 + wave) * 4;
    if (n0 >= N_NODES) return;
    const uint4* t4 = (const uint4*)tb;

    int eb[5];
#pragma unroll
    for (int k = 0; k < 5; ++k) eb[k] = off[n0 + k];

    unsigned int idx[4][4];
#pragma unroll
    for (int k = 0; k < 4; ++k) {
        int e0 = eb[k], e1 = eb[k + 1];
#pragma unroll
        for (int j = 0; j < 4; ++j) {
            int i = e0 + slot + j * 8;
            unsigned int av = csr_src[i];
            idx[k][j] = (i < e1) ? av : ZROW;
        }
    }
    uint4 tv[4][4];
#pragma unroll
    for (int k = 0; k < 4; ++k)
#pragma unroll
        for (int j = 0; j < 4; ++j)
            tv[k][j] = t4[(size_t)idx[k][j] * 8 + ch8];

#pragma unroll
    for (int k = 0; k < 4; ++k) {
        f32x2 s01 = {0.f, 0.f}, s23 = {0.f, 0.f}, s45 = {0.f, 0.f}, s67 = {0.f, 0.f};
        ACC8(tv[k][0]);
        ACC8(tv[k][1]);
        ACC8(tv[k][2]);
        ACC8(tv[k][3]);
        const int e1 = eb[k + 1];
        for (int e = eb[k] + 32; e < e1; e += 32) {   // rare tail
#pragma unroll
            for (int j = 0; j < 4; ++j) {
                int i = e + slot + j * 8;
                unsigned int av = csr_src[i];
                av = (i < e1) ? av : ZROW;
                uint4 v = t4[(size_t)av * 8 + ch8];
                ACC8(v);
            }
        }
        float s[8] = {s01.x, s01.y, s23.x, s23.y, s45.x, s45.y, s67.x, s67.y};
#pragma unroll
        for (int d = 8; d <= 32; d <<= 1) {
#pragma unroll
            for (int j = 0; j < 8; ++j) s[j] += __shfl_xor(s[j], d, 64);
        }
        // h2 channels (all lanes; replicated per ch8 group)
        const float4 b0 = ((const float4*)b)[ch8 * 2];
        const float4 b1 = ((const float4*)b)[ch8 * 2 + 1];
        float r[8];
        r[0] = fmaxf(s[0] + b0.x, 0.f);
        r[1] = fmaxf(s[1] + b0.y, 0.f);
        r[2] = fmaxf(s[2] + b0.z, 0.f);
        r[3] = fmaxf(s[3] + b0.w, 0.f);
        r[4] = fmaxf(s[4] + b1.x, 0.f);
        r[5] = fmaxf(s[5] + b1.y, 0.f);
        r[6] = fmaxf(s[6] + b1.z, 0.f);
        r[7] = fmaxf(s[7] + b1.w, 0.f);
        float p[7];
#pragma unroll
        for (int j = 0; j < 7; ++j) {
            const float4 wa = *(const float4*)(W3 + j * 64 + ch8 * 8);
            const float4 wb = *(const float4*)(W3 + j * 64 + ch8 * 8 + 4);
            float t = r[0] * wa.x + r[1] * wa.y + r[2] * wa.z + r[3] * wa.w
                    + r[4] * wb.x + r[5] * wb.y + r[6] * wb.z + r[7] * wb.w;
            t += __shfl_xor(t, 1, 64);
            t += __shfl_xor(t, 2, 64);
            t += __shfl_xor(t, 4, 64);
            p[j] = t;
        }
        if (lane == 0) {
            uint4 w;
            w.x = pk_bf16(p[0], p[1]);
            w.y = pk_bf16(p[2], p[3]);
            w.z = pk_bf16(p[4], p[5]);
            w.w = pk_bf16(p[6], 0.f);
            *(uint4*)(t3 + (size_t)(n0 + k) * 4) = w;
        }
    }
}

// 7-ch gather (K=4) + bias + log_softmax (bf16 t3, 16 B rows).
__global__ __launch_bounds__(256) void gather7_lsm(const int* __restrict__ off,
                                                   const unsigned int* __restrict__ csr_src,
                                                   const unsigned int* __restrict__ t3,
                                                   const float* __restrict__ b,
                                                   float* __restrict__ out) {
    const int wave = threadIdx.x >> 6;
    const int lane = threadIdx.x & 63;
    const int slot = lane >> 1;
    const int h    = lane & 1;
    const int n0 = (blockIdx.x * 4 + wave) * 4;
    if (n0 >= N_NODES) return;
    const uint2* t2 = (const uint2*)t3;

    int eb[5];
#pragma unroll
    for (int k = 0; k < 5; ++k) eb[k] = off[n0 + k];

    unsigned int idx[4];
#pragma unroll
    for (int k = 0; k < 4; ++k) {
        int i = eb[k] + slot;
        unsigned int av = csr_src[i];
        idx[k] = (i < eb[k + 1]) ? av : ZROW;
    }
    uint2 tv[4];
#pragma unroll
    for (int k = 0; k < 4; ++k) tv[k] = t2[(size_t)idx[k] * 2 + h];

#pragma unroll
    for (int k = 0; k < 4; ++k) {
        float sx = __uint_as_float(tv[k].x << 16);
        float sy = __uint_as_float(tv[k].x & 0xFFFF0000u);
        float sz = __uint_as_float(tv[k].y << 16);
        float sw = __uint_as_float(tv[k].y & 0xFFFF0000u);
        const int e1 = eb[k + 1];
        for (int e = eb[k] + 32; e < e1; e += 32) {   // rare tail
            int i = e + slot;
            unsigned int av = csr_src[i];
            av = (i < e1) ? av : ZROW;
            uint2 v = t2[(size_t)av * 2 + h];
            sx += __uint_as_float(v.x << 16);
            sy += __uint_as_float(v.x & 0xFFFF0000u);
            sz += __uint_as_float(v.y << 16);
            sw += __uint_as_float(v.y & 0xFFFF0000u);
        }
#pragma unroll
        for (int d = 2; d <= 32; d <<= 1) {
            sx += __shfl_xor(sx, d, 64); sy += __shfl_xor(sy, d, 64);
            sz += __shfl_xor(sz, d, 64); sw += __shfl_xor(sw, d, 64);
        }
        float z0 = sx + b[h * 4 + 0];
        float z1 = sy + b[h * 4 + 1];
        float z2 = sz + b[h * 4 + 2];
        float z3 = (h == 0) ? (sw + b[3]) : -1e30f;
        float m = fmaxf(fmaxf(z0, z1), fmaxf(z2, z3));
        m = fmaxf(m, __shfl_xor(m, 1, 64));
        float ex = __expf(z0 - m) + __expf(z1 - m) + __expf(z2 - m) + __expf(z3 - m);
        ex += __shfl_xor(ex, 1, 64);
        float l = m + __logf(ex);
        if (lane < 2) {
            float* o = out + (size_t)(n0 + k) * 7 + h * 4;
            o[0] = z0 - l; o[1] = z1 - l; o[2] = z2 - l;
            if (h == 0) o[3] = z3 - l;
        }
    }
}

extern "C" void kernel_launch(void* const* d_in, const int* in_sizes, int n_in,
                              void* d_out, int out_size, void* d_ws, size_t ws_size,
                              hipStream_t stream) {
    const float* x  = (const float*)d_in[0];
    const int*   ei = (const int*)d_in[1];
    const float* W1 = (const float*)d_in[2];
    const float* b1 = (const float*)d_in[3];
    const float* W2 = (const float*)d_in[4];
    const float* b2 = (const float*)d_in[5];
    const float* W3 = (const float*)d_in[6];
    const float* b3 = (const float*)d_in[7];
    float* out = (float*)d_out;

    const int* src = ei;
    const int* dst = ei + N_EDGES;

    // workspace (round-3 layout):
    //   A (12.8 MB): buckets (8 MB, dead after build_csr) -> bf16 t table
    //                (6.4 MB + 128 B zero-row at ZROW)
    //   B (12.8 MB): Hbf (first 6.4 MB) -> t3 (dead Hbf reused; +ZROW row)
    //   then csr (6.4 MB; over-read <=31 u32 lands in off), off, gcursor, Wb1/Wb2
    float* A = (float*)d_ws;
    float* B = A + (size_t)N_NODES * C;
    unsigned int* csr = (unsigned int*)(B + (size_t)N_NODES * C);
    int* off     = (int*)(csr + N_EDGES);          // 50001
    int* gcursor = off + N_NODES + 8;              // 196
    unsigned int* Wb1 = (unsigned int*)(gcursor + 256);   // 2048 u32
    unsigned int* Wb2 = Wb1 + 2048;                       // 2048 u32
    unsigned int* buckets = (unsigned int*)A;
    unsigned int* Abf     = (unsigned int*)A;      // bf16 t-table view
    unsigned int* Hbf     = (unsigned int*)B;      // bf16 h-table view
    unsigned int* T3      = (unsigned int*)B;      // t3 reuses Hbf (dead by then)

    const int mfmagrid = (N_NODES + 63) / 64;      // 782 blocks x 4 waves
    const int ngrid4   = (N_NODES + 15) / 16;      // 3125 blocks, 16 nodes each

    // ---- prep: pack W1/W2 + zero gcursor
    prep<<<17, 256, 0, stream>>>(W1, W2, Wb1, Wb2, gcursor);

    // ---- CSR build
    bin_kernel<<<(N_EDGES + CHUNK - 1) / CHUNK, 256, 0, stream>>>(src, dst, buckets, gcursor);
    build_csr<<<NB, 256, 0, stream>>>(buckets, gcursor, csr, off);

    // ---- layer 1 (Abf aliases buckets: must follow build_csr)
    linear64_mfma_x<<<mfmagrid, 256, 0, stream>>>(x, Wb1, Abf);
    gather64b<<<ngrid4, 256, 0, stream>>>(off, csr, Abf, b1, Hbf);

    // ---- layer 2 linear
    linear64_mfma<<<mfmagrid, 256, 0, stream>>>(Hbf, Wb2, Abf);

    // ---- layer 2 gather + fused layer-3 linear (h2 never hits memory)
    gather64b_w3<<<ngrid4, 256, 0, stream>>>(off, csr, Abf, b2, W3, T3);

    // ---- layer 3 aggregation + log_softmax
    gather7_lsm<<<ngrid4, 256, 0, stream>>>(off, csr, T3, b3, out);
}